// Round 4
// baseline (895.918 us; speedup 1.0000x reference)
//
#include <hip/hip_runtime.h>

#define NN 50000
#define NE 400000
#define NG 32
#define SLOPE 0.2f

typedef __attribute__((ext_vector_type(4))) float f32x4;
typedef __attribute__((ext_vector_type(8))) short s16x8;

__device__ __forceinline__ float lrelu(float v) { return v > 0.f ? v : SLOPE * v; }
__device__ __forceinline__ unsigned short f2bf(float f) {
    union { float f; unsigned u; } c; c.f = f;
    unsigned r = c.u + 0x7fffu + ((c.u >> 16) & 1u);
    return (unsigned short)(r >> 16);
}
__device__ __forceinline__ float bf2f(unsigned short b) {
    union { unsigned u; float f; } c; c.u = ((unsigned)b) << 16; return c.f;
}
__device__ __forceinline__ f32x4 unpack_bf4(uint2 u) {
    f32x4 r;
    r[0] = bf2f((unsigned short)(u.x & 0xffff));
    r[1] = bf2f((unsigned short)(u.x >> 16));
    r[2] = bf2f((unsigned short)(u.y & 0xffff));
    r[3] = bf2f((unsigned short)(u.y >> 16));
    return r;
}
__device__ __forceinline__ uint2 pack_bf4(f32x4 v) {
    uint2 u;
    u.x = (unsigned)f2bf(v[0]) | ((unsigned)f2bf(v[1]) << 16);
    u.y = (unsigned)f2bf(v[2]) | ((unsigned)f2bf(v[3]) << 16);
    return u;
}

// ---------------- CSR build ----------------
__global__ __launch_bounds__(256) void k_hist(const int* __restrict__ dst, int* __restrict__ deg) {
    int e = blockIdx.x * 256 + threadIdx.x;
    if (e < NE) atomicAdd(&deg[dst[e]], 1);
}

#define SCAN_C 49
__global__ __launch_bounds__(1024) void k_scan(const int* __restrict__ deg,
                                               int* __restrict__ rowptr, int* __restrict__ cursor) {
    __shared__ int ps[1024];
    const int t = threadIdx.x;
    const int base = t * SCAN_C;
    int s = 0;
    for (int j = 0; j < SCAN_C; ++j) { int idx = base + j; if (idx < NN) s += deg[idx]; }
    ps[t] = s;
    __syncthreads();
    for (int off = 1; off < 1024; off <<= 1) {
        int v = (t >= off) ? ps[t - off] : 0;
        __syncthreads();
        ps[t] += v;
        __syncthreads();
    }
    int run = (t == 0) ? 0 : ps[t - 1];
    for (int j = 0; j < SCAN_C; ++j) {
        int idx = base + j;
        if (idx < NN) { rowptr[idx] = run; cursor[idx] = run; run += deg[idx]; }
    }
    if (t == 1023) rowptr[NN] = NE;
}

__global__ __launch_bounds__(256) void k_perm(const int* __restrict__ dst,
                                              int* __restrict__ cursor, int* __restrict__ eid) {
    int e = blockIdx.x * 256 + threadIdx.x;
    if (e < NE) { int p = atomicAdd(&cursor[dst[e]], 1); eid[p] = e; }
}

// ---------------- one-time: w3 -> bf16, [n][k], XOR-swizzled ----------------
__global__ __launch_bounds__(256) void k_w3prep(const float* __restrict__ w3,
                                                unsigned short* __restrict__ w3t_g) {
    const int v = blockIdx.x * 256 + threadIdx.x;  // v = k*512 + n
    if (v >= 64 * 512) return;
    const int k = v >> 9, n = v & 511;
    const int byte = (n << 7) | ((k << 1) ^ ((n & 7) << 4));
    *(unsigned short*)((char*)w3t_g + byte) = f2bf(w3[v]);
}

// ---------------- EdgeMLP: 3->128->64 (h2 bf16) + x-gather + b3-term msg init ----------------
__global__ __launch_bounds__(128) void k_mlp(
    const float* __restrict__ ea,
    const float* __restrict__ w1, const float* __restrict__ b1,
    const float* __restrict__ w2, const float* __restrict__ b2,
    const int* __restrict__ src, const float* __restrict__ x,
    const float* __restrict__ b3,
    unsigned short* __restrict__ h2, unsigned short* __restrict__ msg)
{
    const int e = blockIdx.x * 128 + threadIdx.x;  // 3125*128 == NE exactly
    const float ea0 = ea[e * 3 + 0], ea1 = ea[e * 3 + 1], ea2 = ea[e * 3 + 2];
    // issue the x gather early so its latency hides under the MLP FMAs
    const int s = src[e];
    const f32x4* __restrict__ xp = (const f32x4*)(x + (size_t)s * 16);
    f32x4 xv0 = xp[0], xv1 = xp[1], xv2 = xp[2], xv3 = xp[3];

    float acc[64];
#pragma unroll
    for (int o = 0; o < 64; ++o) acc[o] = b2[o];
#pragma unroll 2
    for (int j = 0; j < 128; ++j) {
        float hj = fmaf(ea0, w1[j], fmaf(ea1, w1[128 + j], fmaf(ea2, w1[256 + j], b1[j])));
        hj = fmaxf(hj, 0.f);
        const float* __restrict__ w2r = w2 + j * 64;
#pragma unroll
        for (int o = 0; o < 64; ++o) acc[o] = fmaf(hj, w2r[o], acc[o]);
    }
    unsigned pk[32];
#pragma unroll
    for (int q = 0; q < 32; ++q) {
        pk[q] = (unsigned)f2bf(fmaxf(acc[2 * q], 0.f)) |
                ((unsigned)f2bf(fmaxf(acc[2 * q + 1], 0.f)) << 16);
    }
    uint4* out = (uint4*)(h2 + (size_t)e * 64);
#pragma unroll
    for (int q = 0; q < 8; ++q)
        out[q] = make_uint4(pk[4 * q], pk[4 * q + 1], pk[4 * q + 2], pk[4 * q + 3]);

    // msg init = x[s] @ B3  (B3 = b3 reshaped [16][32])
    f32x4 m[8];
#pragma unroll
    for (int o4 = 0; o4 < 8; ++o4) m[o4] = (f32x4){0.f, 0.f, 0.f, 0.f};
#pragma unroll
    for (int i = 0; i < 16; ++i) {
        const float xi = (i < 4 ? xv0 : i < 8 ? xv1 : i < 12 ? xv2 : xv3)[i & 3];
        const f32x4* __restrict__ bp = (const f32x4*)(b3 + i * 32);
#pragma unroll
        for (int o4 = 0; o4 < 8; ++o4) {
            f32x4 bv = bp[o4];
#pragma unroll
            for (int c = 0; c < 4; ++c) m[o4][c] = fmaf(xi, bv[c], m[o4][c]);
        }
    }
    uint2 mo[8];
#pragma unroll
    for (int o4 = 0; o4 < 8; ++o4) mo[o4] = pack_bf4(m[o4]);
    uint4* mp = (uint4*)(msg + (size_t)e * 32);
#pragma unroll
    for (int q = 0; q < 4; ++q)
        mp[q] = make_uint4(mo[2 * q].x, mo[2 * q].y, mo[2 * q + 1].x, mo[2 * q + 1].y);
}

// ---------------- msg GEMM: lane-owns-edge, zero barriers in main loop ----------------
// D[n][e] = sum_k w3t[n][k] * h2[e][k]  (A = w3t from LDS, B = h2 from global).
// C/D layout: col(lane&15)=edge, row((lane>>4)*4+reg)=n-within-fragment.
// n = fnn*16 + lg*4 + q  ->  o = (fnn&1)*16 + lg*4 + q,  i = fnn>>1.
// Lane accumulates p[fnn&1][q] += x[src[e]][fnn>>1] * D; writes its own 8 msg values.
#define MSG_GRID 512
#define MSG_WAVES (MSG_GRID * 8)
#define NTILE16 (NE / 16)
__global__ __launch_bounds__(512, 4) void k_msg(
    const unsigned short* __restrict__ h2, const unsigned short* __restrict__ w3t_g,
    const int* __restrict__ src, const float* __restrict__ x,
    unsigned short* __restrict__ msg)
{
    __shared__ unsigned short w3t[512 * 64];  // 64 KB, pre-swizzled
    const int t = threadIdx.x;
    {
        const uint4* g = (const uint4*)w3t_g;
        uint4* l = (uint4*)w3t;
        for (int v = t; v < 4096; v += 512) l[v] = g[v];
    }
    __syncthreads();

    const int wid = t >> 6, lane = t & 63;
    const int lr = lane & 15, lg = lane >> 4;

    for (int tile = blockIdx.x * 8 + wid; tile < NTILE16; tile += MSG_WAVES) {
        const int e = tile * 16 + lr;
        // B fragments: h2[e][k], k-halves
        const s16x8* __restrict__ hp = (const s16x8*)(h2 + (size_t)e * 64 + lg * 8);
        s16x8 b0 = hp[0];   // k = lg*8
        s16x8 b1 = hp[4];   // k = 32 + lg*8
        // this lane's edge source features
        const int sn = src[e];
        const f32x4* __restrict__ xp = (const f32x4*)(x + (size_t)sn * 16);
        f32x4 x0 = xp[0], x1 = xp[1], x2 = xp[2], x3 = xp[3];
        // p init from msg (b3 term written by k_mlp)
        unsigned short* mp = msg + (size_t)e * 32 + lg * 4;
        f32x4 p0 = unpack_bf4(*(const uint2*)mp);
        f32x4 p1 = unpack_bf4(*(const uint2*)(mp + 16));

#pragma unroll
        for (int fnn = 0; fnn < 32; ++fnn) {
            const int n = fnn * 16 + lr;
            const char* __restrict__ arow = (const char*)w3t + (n << 7);
            const int swz = (n & 7) << 4;
            s16x8 a0 = *(const s16x8*)(arow + ((lg * 16) ^ swz));
            s16x8 a1 = *(const s16x8*)(arow + ((64 + lg * 16) ^ swz));
            f32x4 acc = (f32x4){0.f, 0.f, 0.f, 0.f};
            acc = __builtin_amdgcn_mfma_f32_16x16x32_bf16(a0, b0, acc, 0, 0, 0);
            acc = __builtin_amdgcn_mfma_f32_16x16x32_bf16(a1, b1, acc, 0, 0, 0);
            const int i = fnn >> 1;
            const f32x4 xsel = (i < 4) ? x0 : (i < 8) ? x1 : (i < 12) ? x2 : x3;
            const float xvv = xsel[i & 3];
            if (fnn & 1) {
#pragma unroll
                for (int q = 0; q < 4; ++q) p1[q] = fmaf(xvv, acc[q], p1[q]);
            } else {
#pragma unroll
                for (int q = 0; q < 4; ++q) p0[q] = fmaf(xvv, acc[q], p0[q]);
            }
        }
        *(uint2*)mp = pack_bf4(p0);
        *(uint2*)(mp + 16) = pack_bf4(p1);
    }
}

// ---------------- aggregate msg by dst (CSR gather) + root transform ----------------
__global__ __launch_bounds__(256) void k_agg(
    const unsigned short* __restrict__ msg, const int* __restrict__ rowptr,
    const int* __restrict__ eid, const float* __restrict__ x,
    const float* __restrict__ rw, const float* __restrict__ cb, float* __restrict__ h1)
{
    const int gid = blockIdx.x * 256 + threadIdx.x;
    const int n = (gid >> 6) * 2 + ((gid & 63) >> 5);  // 2 nodes per wave
    if (n >= NN) return;
    const int o = gid & 31;
    const int r0 = rowptr[n], r1 = rowptr[n + 1];
    float acc = 0.f;
    for (int j = r0; j < r1; ++j)
        acc += bf2f(msg[(size_t)eid[j] * 32 + o]);
    const float* __restrict__ xr = x + (size_t)n * 16;
    float root = cb[o];
#pragma unroll
    for (int i = 0; i < 16; ++i) root = fmaf(xr[i], rw[i * 32 + o], root);
    h1[(size_t)n * 32 + o] = fmaxf(acc + root, 0.f);
}

// ---------------- GAT: node transform + attention coefficients ----------------
template <int FI>
__global__ __launch_bounds__(256) void k_gat_h(
    const float* __restrict__ hin, const float* __restrict__ W,
    const float* __restrict__ av_s, const float* __restrict__ av_d,
    float* __restrict__ h, float* __restrict__ as_v, float* __restrict__ ad_v)
{
    const int n = blockIdx.x * 256 + threadIdx.x;
    if (n >= NN) return;
    float acc[64];
#pragma unroll
    for (int o = 0; o < 64; ++o) acc[o] = 0.f;
#pragma unroll 2
    for (int i = 0; i < FI; ++i) {
        const float xi = hin[(size_t)n * FI + i];
        const float* __restrict__ wr = W + i * 64;
#pragma unroll
        for (int o = 0; o < 64; ++o) acc[o] = fmaf(xi, wr[o], acc[o]);
    }
    float s = 0.f, d = 0.f;
#pragma unroll
    for (int o = 0; o < 64; ++o) {
        h[(size_t)n * 64 + o] = acc[o];
        s = fmaf(acc[o], av_s[o], s);
        d = fmaf(acc[o], av_d[o], d);
    }
    as_v[n] = s;
    ad_v[n] = d;
}

// ---------------- GAT: per-node softmax + weighted gather (one wave per node) ----------------
__global__ __launch_bounds__(256) void k_gat_node(
    const int* __restrict__ rowptr, const int* __restrict__ eid, const int* __restrict__ src,
    const float* __restrict__ h, const float* __restrict__ as_v, const float* __restrict__ ad_v,
    const float* __restrict__ b, float* __restrict__ out)
{
    const int n = (blockIdx.x * 256 + threadIdx.x) >> 6;
    if (n >= NN) return;
    const int lane = threadIdx.x & 63;
    const int r0 = rowptr[n], r1 = rowptr[n + 1];
    const float adn = ad_v[n];
    const float l_self = lrelu(as_v[n] + adn);
    float m = l_self;
    for (int j = r0 + lane; j < r1; j += 64)
        m = fmaxf(m, lrelu(as_v[src[eid[j]]] + adn));
#pragma unroll
    for (int off = 32; off; off >>= 1) m = fmaxf(m, __shfl_xor(m, off));
    float s = 0.f;
    for (int j = r0 + lane; j < r1; j += 64)
        s += expf(lrelu(as_v[src[eid[j]]] + adn) - m);
#pragma unroll
    for (int off = 32; off; off >>= 1) s += __shfl_xor(s, off);
    const float w_self = expf(l_self - m);
    s += w_self;
    float acc = w_self * h[(size_t)n * 64 + lane];
    for (int j = r0; j < r1; ++j) {
        const int sn = src[eid[j]];
        const float w = expf(lrelu(as_v[sn] + adn) - m);
        acc = fmaf(w, h[(size_t)sn * 64 + lane], acc);
    }
    out[(size_t)n * 64 + lane] = fmaxf(acc / s + b[lane], 0.f);
}

// ---------------- global mean pool ----------------
__global__ __launch_bounds__(256) void k_pool1(
    const float* __restrict__ h, const int* __restrict__ batch,
    float* __restrict__ gsum, float* __restrict__ gcnt)
{
    __shared__ float ls[NG * 64];
    __shared__ float lc[NG];
    for (int j = threadIdx.x; j < NG * 64; j += 256) ls[j] = 0.f;
    if (threadIdx.x < NG) lc[threadIdx.x] = 0.f;
    __syncthreads();
    const int base = blockIdx.x * 512;
    for (int idx = threadIdx.x; idx < 512 * 64; idx += 256) {
        const int nl = idx >> 6, f = idx & 63;
        const int n = base + nl;
        if (n < NN) {
            const int g = batch[n];
            atomicAdd(&ls[g * 64 + f], h[(size_t)n * 64 + f]);
            if (f == 0) atomicAdd(&lc[g], 1.f);
        }
    }
    __syncthreads();
    for (int j = threadIdx.x; j < NG * 64; j += 256) atomicAdd(&gsum[j], ls[j]);
    if (threadIdx.x < NG) atomicAdd(&gcnt[threadIdx.x], lc[threadIdx.x]);
}

__global__ __launch_bounds__(256) void k_pool2(
    const float* __restrict__ gsum, const float* __restrict__ gcnt, float* __restrict__ out)
{
    const int idx = blockIdx.x * 256 + threadIdx.x;
    if (idx >= NG * 64) return;
    out[idx] = gsum[idx] / fmaxf(gcnt[idx >> 6], 1.f);
}

extern "C" void kernel_launch(void* const* d_in, const int* in_sizes, int n_in,
                              void* d_out, int out_size, void* d_ws, size_t ws_size,
                              hipStream_t stream)
{
    const float* x     = (const float*)d_in[0];
    const float* ea    = (const float*)d_in[1];
    const int*   ei    = (const int*)d_in[2];
    const int*   batch = (const int*)d_in[3];
    const float* w1 = (const float*)d_in[4];   const float* b1 = (const float*)d_in[5];
    const float* w2 = (const float*)d_in[6];   const float* b2 = (const float*)d_in[7];
    const float* w3 = (const float*)d_in[8];   const float* b3 = (const float*)d_in[9];
    const float* rw = (const float*)d_in[10];  const float* cb = (const float*)d_in[11];
    const float* g1w  = (const float*)d_in[12]; const float* g1as = (const float*)d_in[13];
    const float* g1ad = (const float*)d_in[14]; const float* g1b  = (const float*)d_in[15];
    const float* g2w  = (const float*)d_in[16]; const float* g2as = (const float*)d_in[17];
    const float* g2ad = (const float*)d_in[18]; const float* g2b  = (const float*)d_in[19];
    const int* src = ei;
    const int* dst = ei + NE;
    float* out = (float*)d_out;
    (void)in_sizes; (void)n_in; (void)out_size; (void)ws_size;

    char* ws = (char*)d_ws;
    size_t off = 0;
    auto alloc = [&](size_t bytes) -> char* {
        char* p = ws + off;
        off += (bytes + 255) & ~(size_t)255;
        return p;
    };
    int*  deg    = (int*)alloc((size_t)NN * 4);
    int*  cursor = (int*)alloc((size_t)NN * 4);
    int*  rowptr = (int*)alloc((size_t)(NN + 1) * 4);
    int*  eid    = (int*)alloc((size_t)NE * 4);
    unsigned short* w3t_g = (unsigned short*)alloc((size_t)64 * 512 * 2);
    unsigned short* h2  = (unsigned short*)alloc((size_t)NE * 64 * 2);  // 51.2 MB, reused below
    unsigned short* msg = (unsigned short*)alloc((size_t)NE * 32 * 2);  // 25.6 MB
    float* h1   = (float*)alloc((size_t)NN * 32 * 4);
    float* as_v = (float*)alloc((size_t)NN * 4);
    float* ad_v = (float*)alloc((size_t)NN * 4);
    float* gsum = (float*)alloc((size_t)NG * 64 * 4);
    float* gcnt = (float*)alloc((size_t)NG * 4);
    // h2 region dead after k_msg; reuse for GAT feature buffers (38.4 MB <= 51.2 MB)
    float* hB = (float*)h2;
    float* hC = (float*)((char*)h2 + (size_t)NN * 64 * 4);
    float* hD = (float*)((char*)h2 + (size_t)NN * 64 * 8);

    hipMemsetAsync(deg, 0, (size_t)NN * 4, stream);
    hipMemsetAsync(gsum, 0, (size_t)NG * 64 * 4, stream);
    hipMemsetAsync(gcnt, 0, (size_t)NG * 4, stream);

    // CSR build
    k_hist<<<(NE + 255) / 256, 256, 0, stream>>>(dst, deg);
    k_scan<<<1, 1024, 0, stream>>>(deg, rowptr, cursor);
    k_perm<<<(NE + 255) / 256, 256, 0, stream>>>(dst, cursor, eid);

    // NNConv
    k_w3prep<<<(64 * 512 + 255) / 256, 256, 0, stream>>>(w3, w3t_g);
    k_mlp<<<NE / 128, 128, 0, stream>>>(ea, w1, b1, w2, b2, src, x, b3, h2, msg);
    k_msg<<<MSG_GRID, 512, 0, stream>>>(h2, w3t_g, src, x, msg);
    k_agg<<<(NN / 2 * 64 + 255) / 256 + 1, 256, 0, stream>>>(msg, rowptr, eid, x, rw, cb, h1);

    // GAT layer 1
    k_gat_h<32><<<(NN + 255) / 256, 256, 0, stream>>>(h1, g1w, g1as, g1ad, hB, as_v, ad_v);
    k_gat_node<<<(NN * 64 + 255) / 256, 256, 0, stream>>>(rowptr, eid, src, hB, as_v, ad_v, g1b, hC);

    // GAT layer 2
    k_gat_h<64><<<(NN + 255) / 256, 256, 0, stream>>>(hC, g2w, g2as, g2ad, hB, as_v, ad_v);
    k_gat_node<<<(NN * 64 + 255) / 256, 256, 0, stream>>>(rowptr, eid, src, hB, as_v, ad_v, g2b, hD);

    // pool
    k_pool1<<<(NN + 511) / 512, 256, 0, stream>>>(hD, batch, gsum, gcnt);
    k_pool2<<<(NG * 64 + 255) / 256, 256, 0, stream>>>(gsum, gcnt, out);
}

// Round 5
// 706.214 us; speedup vs baseline: 1.2686x; 1.2686x over previous
//
#include <hip/hip_runtime.h>

#define NN 50000
#define NE 400000
#define NG 32
#define SLOPE 0.2f

typedef __attribute__((ext_vector_type(4))) float f32x4;
typedef __attribute__((ext_vector_type(8))) short s16x8;

__device__ __forceinline__ float lrelu(float v) { return v > 0.f ? v : SLOPE * v; }
__device__ __forceinline__ unsigned short f2bf(float f) {
    union { float f; unsigned u; } c; c.f = f;
    unsigned r = c.u + 0x7fffu + ((c.u >> 16) & 1u);
    return (unsigned short)(r >> 16);
}
__device__ __forceinline__ float bf2f(unsigned short b) {
    union { unsigned u; float f; } c; c.u = ((unsigned)b) << 16; return c.f;
}
__device__ __forceinline__ uint2 pack_bf4(f32x4 v) {
    uint2 u;
    u.x = (unsigned)f2bf(v[0]) | ((unsigned)f2bf(v[1]) << 16);
    u.y = (unsigned)f2bf(v[2]) | ((unsigned)f2bf(v[3]) << 16);
    return u;
}

// ---------------- CSR build ----------------
__global__ __launch_bounds__(256) void k_hist(const int* __restrict__ dst, int* __restrict__ deg) {
    int e = blockIdx.x * 256 + threadIdx.x;
    if (e < NE) atomicAdd(&deg[dst[e]], 1);
}

#define SCAN_C 49
__global__ __launch_bounds__(1024) void k_scan(const int* __restrict__ deg,
                                               int* __restrict__ rowptr, int* __restrict__ cursor) {
    __shared__ int ps[1024];
    const int t = threadIdx.x;
    const int base = t * SCAN_C;
    int s = 0;
    for (int j = 0; j < SCAN_C; ++j) { int idx = base + j; if (idx < NN) s += deg[idx]; }
    ps[t] = s;
    __syncthreads();
    for (int off = 1; off < 1024; off <<= 1) {
        int v = (t >= off) ? ps[t - off] : 0;
        __syncthreads();
        ps[t] += v;
        __syncthreads();
    }
    int run = (t == 0) ? 0 : ps[t - 1];
    for (int j = 0; j < SCAN_C; ++j) {
        int idx = base + j;
        if (idx < NN) { rowptr[idx] = run; cursor[idx] = run; run += deg[idx]; }
    }
    if (t == 1023) rowptr[NN] = NE;
}

__global__ __launch_bounds__(256) void k_perm(const int* __restrict__ dst,
                                              int* __restrict__ cursor, int* __restrict__ eid) {
    int e = blockIdx.x * 256 + threadIdx.x;
    if (e < NE) { int p = atomicAdd(&cursor[dst[e]], 1); eid[p] = e; }
}

// ---------------- one-time: w3 -> bf16, [n][k], XOR-swizzled ----------------
__global__ __launch_bounds__(256) void k_w3prep(const float* __restrict__ w3,
                                                unsigned short* __restrict__ w3t_g) {
    const int v = blockIdx.x * 256 + threadIdx.x;  // v = k*512 + n
    if (v >= 64 * 512) return;
    const int k = v >> 9, n = v & 511;
    const int byte = (n << 7) | ((k << 1) ^ ((n & 7) << 4));
    *(unsigned short*)((char*)w3t_g + byte) = f2bf(w3[v]);
}

// ---------------- fused NNConv edge pipeline: MLP -> MFMA GEMM -> msg ----------------
// Per wave: 64 edges. Phase 1 (1 lane = 1 edge): EdgeMLP 3->128->64 from LDS weights,
// result packed bf16 in 32 regs. Phase 2 (4 sub-tiles of 16 edges): owner lanes stage
// h2 fragments to a 2KB/wave LDS slab; lane-owns-edge MFMA vs LDS-resident w3t
// (R4-verified mapping); b3 term from LDS; msg written via LDS transpose as one
// contiguous 1KB uint4 store per sub-tile. No block barriers after staging.
#define FUSED_GRID 256
__global__ __launch_bounds__(512) void k_fused(
    const float* __restrict__ ea,
    const float* __restrict__ w1, const float* __restrict__ b1,
    const float* __restrict__ w2, const float* __restrict__ b2,
    const unsigned short* __restrict__ w3t_g, const float* __restrict__ b3,
    const int* __restrict__ src, const float* __restrict__ x,
    unsigned short* __restrict__ msg)
{
    __shared__ __align__(16) unsigned short w3t[512 * 64];  // 64 KB, pre-swizzled
    __shared__ __align__(16) float w2s[128 * 64];           // 32 KB
    __shared__ __align__(16) float w1s[384];
    __shared__ __align__(16) float b1s[128];
    __shared__ __align__(16) float b2s[64];
    __shared__ __align__(16) float b3s[512];
    __shared__ __align__(16) unsigned h2st[8][512];         // 2 KB per wave

    const int t = threadIdx.x;
    {
        const uint4* g = (const uint4*)w3t_g;
        uint4* l = (uint4*)w3t;
        for (int v = t; v < 4096; v += 512) l[v] = g[v];
    }
    {
        const uint4* g = (const uint4*)w2;
        uint4* l = (uint4*)w2s;
        for (int v = t; v < 2048; v += 512) l[v] = g[v];
    }
    if (t < 384) w1s[t] = w1[t];
    if (t < 128) b1s[t] = b1[t];
    if (t < 64)  b2s[t] = b2[t];
    b3s[t & 511] = b3[t & 511];
    __syncthreads();

    const int wid = t >> 6, lane = t & 63;
    const int lr = lane & 15, lg = lane >> 4;
    char* h2w = (char*)h2st[wid];

    for (int chunk = blockIdx.x * 8 + wid; chunk < NE / 64; chunk += FUSED_GRID * 8) {
        const int e = chunk * 64 + lane;
        const float ea0 = ea[e * 3 + 0], ea1 = ea[e * 3 + 1], ea2 = ea[e * 3 + 2];

        // ---- Phase 1: EdgeMLP (all weights in LDS) ----
        float acc[64];
#pragma unroll
        for (int o = 0; o < 64; ++o) acc[o] = b2s[o];
#pragma unroll 2
        for (int j = 0; j < 128; ++j) {
            float hj = fmaf(ea0, w1s[j], fmaf(ea1, w1s[128 + j], fmaf(ea2, w1s[256 + j], b1s[j])));
            hj = fmaxf(hj, 0.f);
            const float* __restrict__ w2r = w2s + j * 64;
#pragma unroll
            for (int o = 0; o < 64; ++o) acc[o] = fmaf(hj, w2r[o], acc[o]);
        }
        unsigned pk[32];
#pragma unroll
        for (int q = 0; q < 32; ++q)
            pk[q] = (unsigned)f2bf(fmaxf(acc[2 * q], 0.f)) |
                    ((unsigned)f2bf(fmaxf(acc[2 * q + 1], 0.f)) << 16);

        // ---- Phase 2: per sub-tile MFMA + epilogue ----
#pragma unroll 1
        for (int st = 0; st < 4; ++st) {
            asm volatile("s_waitcnt lgkmcnt(0)" ::: "memory");  // prior iter's LDS reads done
            if (lg == st) {
                // owner lanes stage their h2 row in fragment order [kc][lg'][lr][16B]
                uint4* dstp = (uint4*)h2w;
#pragma unroll
                for (int kc = 0; kc < 2; ++kc)
#pragma unroll
                    for (int lgp = 0; lgp < 4; ++lgp)
                        dstp[kc * 64 + lgp * 16 + lr] =
                            make_uint4(pk[kc * 16 + lgp * 4 + 0], pk[kc * 16 + lgp * 4 + 1],
                                       pk[kc * 16 + lgp * 4 + 2], pk[kc * 16 + lgp * 4 + 3]);
            }
            asm volatile("s_waitcnt lgkmcnt(0)" ::: "memory");  // staging visible wave-wide

            s16x8 bb0 = *(const s16x8*)(h2w + lg * 256 + lr * 16);          // k = lg*8
            s16x8 bb1 = *(const s16x8*)(h2w + 1024 + lg * 256 + lr * 16);   // k = 32+lg*8

            const int e16 = chunk * 64 + st * 16 + lr;
            const int sn = src[e16];
            const f32x4* __restrict__ xp = (const f32x4*)(x + (size_t)sn * 16);
            f32x4 x0 = xp[0], x1 = xp[1], x2 = xp[2], x3 = xp[3];

            // p init = b3 term: p[o] = sum_i x_i * b3[i*32+o]
            f32x4 p0 = (f32x4){0.f, 0.f, 0.f, 0.f};
            f32x4 p1 = (f32x4){0.f, 0.f, 0.f, 0.f};
#pragma unroll
            for (int i = 0; i < 16; ++i) {
                const float xi = (i < 4 ? x0 : i < 8 ? x1 : i < 12 ? x2 : x3)[i & 3];
                f32x4 bv0 = *(const f32x4*)(b3s + i * 32 + lg * 4);
                f32x4 bv1 = *(const f32x4*)(b3s + i * 32 + 16 + lg * 4);
#pragma unroll
                for (int q = 0; q < 4; ++q) {
                    p0[q] = fmaf(xi, bv0[q], p0[q]);
                    p1[q] = fmaf(xi, bv1[q], p1[q]);
                }
            }

#pragma unroll
            for (int fnn = 0; fnn < 32; ++fnn) {
                const int n = fnn * 16 + lr;
                const char* __restrict__ arow = (const char*)w3t + (n << 7);
                const int swz = (n & 7) << 4;
                s16x8 a0 = *(const s16x8*)(arow + ((lg * 16) ^ swz));
                s16x8 a1 = *(const s16x8*)(arow + ((64 + lg * 16) ^ swz));
                f32x4 am = (f32x4){0.f, 0.f, 0.f, 0.f};
                am = __builtin_amdgcn_mfma_f32_16x16x32_bf16(a0, bb0, am, 0, 0, 0);
                am = __builtin_amdgcn_mfma_f32_16x16x32_bf16(a1, bb1, am, 0, 0, 0);
                const int i = fnn >> 1;
                const float xvv = (i < 4 ? x0 : i < 8 ? x1 : i < 12 ? x2 : x3)[i & 3];
                if (fnn & 1) {
#pragma unroll
                    for (int q = 0; q < 4; ++q) p1[q] = fmaf(xvv, am[q], p1[q]);
                } else {
#pragma unroll
                    for (int q = 0; q < 4; ++q) p0[q] = fmaf(xvv, am[q], p0[q]);
                }
            }

            // LDS transpose (reuse first 1KB of slab) -> one contiguous 1KB store
            *(uint2*)(h2w + lr * 64 + lg * 8)      = pack_bf4(p0);
            *(uint2*)(h2w + lr * 64 + 32 + lg * 8) = pack_bf4(p1);
            asm volatile("s_waitcnt lgkmcnt(0)" ::: "memory");
            uint4 u = *(const uint4*)(h2w + lane * 16);
            *(uint4*)((char*)msg + (size_t)(chunk * 64 + st * 16) * 64 + lane * 16) = u;
        }
    }
}

// ---------------- aggregate msg by dst (CSR gather) + root transform ----------------
__global__ __launch_bounds__(256) void k_agg(
    const unsigned short* __restrict__ msg, const int* __restrict__ rowptr,
    const int* __restrict__ eid, const float* __restrict__ x,
    const float* __restrict__ rw, const float* __restrict__ cb, float* __restrict__ h1)
{
    const int gid = blockIdx.x * 256 + threadIdx.x;
    const int n = (gid >> 6) * 2 + ((gid & 63) >> 5);  // 2 nodes per wave
    if (n >= NN) return;
    const int o = gid & 31;
    const int r0 = rowptr[n], r1 = rowptr[n + 1];
    float acc = 0.f;
    for (int j = r0; j < r1; ++j)
        acc += bf2f(msg[(size_t)eid[j] * 32 + o]);
    const float* __restrict__ xr = x + (size_t)n * 16;
    float root = cb[o];
#pragma unroll
    for (int i = 0; i < 16; ++i) root = fmaf(xr[i], rw[i * 32 + o], root);
    h1[(size_t)n * 32 + o] = fmaxf(acc + root, 0.f);
}

// ---------------- GAT: node transform + attention coefficients ----------------
template <int FI>
__global__ __launch_bounds__(256) void k_gat_h(
    const float* __restrict__ hin, const float* __restrict__ W,
    const float* __restrict__ av_s, const float* __restrict__ av_d,
    float* __restrict__ h, float* __restrict__ as_v, float* __restrict__ ad_v)
{
    const int n = blockIdx.x * 256 + threadIdx.x;
    if (n >= NN) return;
    float acc[64];
#pragma unroll
    for (int o = 0; o < 64; ++o) acc[o] = 0.f;
#pragma unroll 2
    for (int i = 0; i < FI; ++i) {
        const float xi = hin[(size_t)n * FI + i];
        const float* __restrict__ wr = W + i * 64;
#pragma unroll
        for (int o = 0; o < 64; ++o) acc[o] = fmaf(xi, wr[o], acc[o]);
    }
    float s = 0.f, d = 0.f;
#pragma unroll
    for (int o = 0; o < 64; ++o) {
        h[(size_t)n * 64 + o] = acc[o];
        s = fmaf(acc[o], av_s[o], s);
        d = fmaf(acc[o], av_d[o], d);
    }
    as_v[n] = s;
    ad_v[n] = d;
}

// ---------------- GAT: per-node softmax + weighted gather (one wave per node) ----------------
__global__ __launch_bounds__(256) void k_gat_node(
    const int* __restrict__ rowptr, const int* __restrict__ eid, const int* __restrict__ src,
    const float* __restrict__ h, const float* __restrict__ as_v, const float* __restrict__ ad_v,
    const float* __restrict__ b, float* __restrict__ out)
{
    const int n = (blockIdx.x * 256 + threadIdx.x) >> 6;
    if (n >= NN) return;
    const int lane = threadIdx.x & 63;
    const int r0 = rowptr[n], r1 = rowptr[n + 1];
    const float adn = ad_v[n];
    const float l_self = lrelu(as_v[n] + adn);
    float m = l_self;
    for (int j = r0 + lane; j < r1; j += 64)
        m = fmaxf(m, lrelu(as_v[src[eid[j]]] + adn));
#pragma unroll
    for (int off = 32; off; off >>= 1) m = fmaxf(m, __shfl_xor(m, off));
    float s = 0.f;
    for (int j = r0 + lane; j < r1; j += 64)
        s += expf(lrelu(as_v[src[eid[j]]] + adn) - m);
#pragma unroll
    for (int off = 32; off; off >>= 1) s += __shfl_xor(s, off);
    const float w_self = expf(l_self - m);
    s += w_self;
    float acc = w_self * h[(size_t)n * 64 + lane];
    for (int j = r0; j < r1; ++j) {
        const int sn = src[eid[j]];
        const float w = expf(lrelu(as_v[sn] + adn) - m);
        acc = fmaf(w, h[(size_t)sn * 64 + lane], acc);
    }
    out[(size_t)n * 64 + lane] = fmaxf(acc / s + b[lane], 0.f);
}

// ---------------- global mean pool ----------------
__global__ __launch_bounds__(256) void k_pool1(
    const float* __restrict__ h, const int* __restrict__ batch,
    float* __restrict__ gsum, float* __restrict__ gcnt)
{
    __shared__ float ls[NG * 64];
    __shared__ float lc[NG];
    for (int j = threadIdx.x; j < NG * 64; j += 256) ls[j] = 0.f;
    if (threadIdx.x < NG) lc[threadIdx.x] = 0.f;
    __syncthreads();
    const int base = blockIdx.x * 512;
    for (int idx = threadIdx.x; idx < 512 * 64; idx += 256) {
        const int nl = idx >> 6, f = idx & 63;
        const int n = base + nl;
        if (n < NN) {
            const int g = batch[n];
            atomicAdd(&ls[g * 64 + f], h[(size_t)n * 64 + f]);
            if (f == 0) atomicAdd(&lc[g], 1.f);
        }
    }
    __syncthreads();
    for (int j = threadIdx.x; j < NG * 64; j += 256) atomicAdd(&gsum[j], ls[j]);
    if (threadIdx.x < NG) atomicAdd(&gcnt[threadIdx.x], lc[threadIdx.x]);
}

__global__ __launch_bounds__(256) void k_pool2(
    const float* __restrict__ gsum, const float* __restrict__ gcnt, float* __restrict__ out)
{
    const int idx = blockIdx.x * 256 + threadIdx.x;
    if (idx >= NG * 64) return;
    out[idx] = gsum[idx] / fmaxf(gcnt[idx >> 6], 1.f);
}

extern "C" void kernel_launch(void* const* d_in, const int* in_sizes, int n_in,
                              void* d_out, int out_size, void* d_ws, size_t ws_size,
                              hipStream_t stream)
{
    const float* x     = (const float*)d_in[0];
    const float* ea    = (const float*)d_in[1];
    const int*   ei    = (const int*)d_in[2];
    const int*   batch = (const int*)d_in[3];
    const float* w1 = (const float*)d_in[4];   const float* b1 = (const float*)d_in[5];
    const float* w2 = (const float*)d_in[6];   const float* b2 = (const float*)d_in[7];
    const float* w3 = (const float*)d_in[8];   const float* b3 = (const float*)d_in[9];
    const float* rw = (const float*)d_in[10];  const float* cb = (const float*)d_in[11];
    const float* g1w  = (const float*)d_in[12]; const float* g1as = (const float*)d_in[13];
    const float* g1ad = (const float*)d_in[14]; const float* g1b  = (const float*)d_in[15];
    const float* g2w  = (const float*)d_in[16]; const float* g2as = (const float*)d_in[17];
    const float* g2ad = (const float*)d_in[18]; const float* g2b  = (const float*)d_in[19];
    const int* src = ei;
    const int* dst = ei + NE;
    float* out = (float*)d_out;
    (void)in_sizes; (void)n_in; (void)out_size; (void)ws_size;

    char* ws = (char*)d_ws;
    size_t off = 0;
    auto alloc = [&](size_t bytes) -> char* {
        char* p = ws + off;
        off += (bytes + 255) & ~(size_t)255;
        return p;
    };
    int*  deg    = (int*)alloc((size_t)NN * 4);
    int*  cursor = (int*)alloc((size_t)NN * 4);
    int*  rowptr = (int*)alloc((size_t)(NN + 1) * 4);
    int*  eid    = (int*)alloc((size_t)NE * 4);
    unsigned short* w3t_g = (unsigned short*)alloc((size_t)64 * 512 * 2);
    unsigned short* msg   = (unsigned short*)alloc((size_t)NE * 32 * 2);  // 25.6 MB
    float* h1   = (float*)alloc((size_t)NN * 32 * 4);
    float* hB   = (float*)alloc((size_t)NN * 64 * 4);
    float* hC   = (float*)alloc((size_t)NN * 64 * 4);
    float* hD   = (float*)alloc((size_t)NN * 64 * 4);
    float* as_v = (float*)alloc((size_t)NN * 4);
    float* ad_v = (float*)alloc((size_t)NN * 4);
    float* gsum = (float*)alloc((size_t)NG * 64 * 4);
    float* gcnt = (float*)alloc((size_t)NG * 4);

    hipMemsetAsync(deg, 0, (size_t)NN * 4, stream);
    hipMemsetAsync(gsum, 0, (size_t)NG * 64 * 4, stream);
    hipMemsetAsync(gcnt, 0, (size_t)NG * 4, stream);

    // CSR build
    k_hist<<<(NE + 255) / 256, 256, 0, stream>>>(dst, deg);
    k_scan<<<1, 1024, 0, stream>>>(deg, rowptr, cursor);
    k_perm<<<(NE + 255) / 256, 256, 0, stream>>>(dst, cursor, eid);

    // NNConv (fused MLP + GEMM)
    k_w3prep<<<(64 * 512 + 255) / 256, 256, 0, stream>>>(w3, w3t_g);
    k_fused<<<FUSED_GRID, 512, 0, stream>>>(ea, w1, b1, w2, b2, w3t_g, b3, src, x, msg);
    k_agg<<<(NN / 2 * 64 + 255) / 256 + 1, 256, 0, stream>>>(msg, rowptr, eid, x, rw, cb, h1);

    // GAT layer 1
    k_gat_h<32><<<(NN + 255) / 256, 256, 0, stream>>>(h1, g1w, g1as, g1ad, hB, as_v, ad_v);
    k_gat_node<<<(NN * 64 + 255) / 256, 256, 0, stream>>>(rowptr, eid, src, hB, as_v, ad_v, g1b, hC);

    // GAT layer 2
    k_gat_h<64><<<(NN + 255) / 256, 256, 0, stream>>>(hC, g2w, g2as, g2ad, hB, as_v, ad_v);
    k_gat_node<<<(NN * 64 + 255) / 256, 256, 0, stream>>>(rowptr, eid, src, hB, as_v, ad_v, g2b, hD);

    // pool
    k_pool1<<<(NN + 511) / 512, 256, 0, stream>>>(hD, batch, gsum, gcnt);
    k_pool2<<<(NG * 64 + 255) / 256, 256, 0, stream>>>(gsum, gcnt, out);
}

// Round 6
// 550.896 us; speedup vs baseline: 1.6263x; 1.2819x over previous
//
#include <hip/hip_runtime.h>

#define NN 50000
#define NE 400000
#define NG 32
#define SLOPE 0.2f

typedef __attribute__((ext_vector_type(4))) float f32x4;
typedef __attribute__((ext_vector_type(8))) short s16x8;

__device__ __forceinline__ float lrelu(float v) { return v > 0.f ? v : SLOPE * v; }
__device__ __forceinline__ unsigned short f2bf(float f) {
    union { float f; unsigned u; } c; c.f = f;
    unsigned r = c.u + 0x7fffu + ((c.u >> 16) & 1u);
    return (unsigned short)(r >> 16);
}
__device__ __forceinline__ float bf2f(unsigned short b) {
    union { unsigned u; float f; } c; c.u = ((unsigned)b) << 16; return c.f;
}
__device__ __forceinline__ uint2 pack_bf4(f32x4 v) {
    uint2 u;
    u.x = (unsigned)f2bf(v[0]) | ((unsigned)f2bf(v[1]) << 16);
    u.y = (unsigned)f2bf(v[2]) | ((unsigned)f2bf(v[3]) << 16);
    return u;
}

// ---------------- CSR build ----------------
__global__ __launch_bounds__(256) void k_hist(const int* __restrict__ dst, int* __restrict__ deg) {
    int e = blockIdx.x * 256 + threadIdx.x;
    if (e < NE) atomicAdd(&deg[dst[e]], 1);
}

#define SCAN_C 49
__global__ __launch_bounds__(1024) void k_scan(const int* __restrict__ deg,
                                               int* __restrict__ rowptr, int* __restrict__ cursor) {
    __shared__ int ps[1024];
    const int t = threadIdx.x;
    const int base = t * SCAN_C;
    int s = 0;
    for (int j = 0; j < SCAN_C; ++j) { int idx = base + j; if (idx < NN) s += deg[idx]; }
    ps[t] = s;
    __syncthreads();
    for (int off = 1; off < 1024; off <<= 1) {
        int v = (t >= off) ? ps[t - off] : 0;
        __syncthreads();
        ps[t] += v;
        __syncthreads();
    }
    int run = (t == 0) ? 0 : ps[t - 1];
    for (int j = 0; j < SCAN_C; ++j) {
        int idx = base + j;
        if (idx < NN) { rowptr[idx] = run; cursor[idx] = run; run += deg[idx]; }
    }
    if (t == 1023) rowptr[NN] = NE;
}

__global__ __launch_bounds__(256) void k_perm(const int* __restrict__ dst,
                                              int* __restrict__ cursor, int* __restrict__ eid) {
    int e = blockIdx.x * 256 + threadIdx.x;
    if (e < NE) { int p = atomicAdd(&cursor[dst[e]], 1); eid[p] = e; }
}

// ---------------- one-time: w3 and w2^T -> bf16, row-major, XOR-swizzled ----------------
__global__ __launch_bounds__(256) void k_wprep(const float* __restrict__ w3,
                                               const float* __restrict__ w2,
                                               unsigned short* __restrict__ w3t_g,
                                               unsigned short* __restrict__ w2t_g) {
    const int v = blockIdx.x * 256 + threadIdx.x;
    if (v < 64 * 512) {  // w3: v = k*512 + n -> w3t[n][k]
        const int k = v >> 9, n = v & 511;
        const int byte = (n << 7) | ((k << 1) ^ ((n & 7) << 4));
        *(unsigned short*)((char*)w3t_g + byte) = f2bf(w3[v]);
    }
    if (v < 128 * 64) {  // w2: v = j*64 + o -> w2t[o][j]
        const int j = v >> 6, o = v & 63;
        const int byte = (o << 8) | ((j << 1) ^ ((o & 7) << 4));
        *(unsigned short*)((char*)w2t_g + byte) = f2bf(w2[v]);
    }
}

// ---------------- fused NNConv edge pipeline: MLP(L1 scalar, L2 MFMA) -> w3 MFMA -> msg ----------
// Per wave, per 16-edge subtile, lane (lr=edge, lg=k-quarter):
//  L1: h1[e=lr][j=m*32+lg*8+i] per-lane (96 FMA) -> packed bf16 = B-fragment of L2 MFMA directly.
//  L2: h2 = relu(w2^T @ h1 + b2) via 16 MFMAs (A=w2t from LDS). D-layout: col=lr, row=o.
//  Redistribute h2 through 2KB/wave slab (XOR swz) into w3-GEMM B-fragments.
//  w3 GEMM (64 MFMAs) + in-register x-contraction + b3 seed; store via slab transpose.
#define FUSED_GRID 256
__global__ __launch_bounds__(512) void k_fused(
    const float* __restrict__ ea,
    const float* __restrict__ w1, const float* __restrict__ b1,
    const unsigned short* __restrict__ w2t_g, const float* __restrict__ b2,
    const unsigned short* __restrict__ w3t_g, const float* __restrict__ b3,
    const int* __restrict__ src, const float* __restrict__ x,
    unsigned short* __restrict__ msg)
{
    __shared__ __align__(16) unsigned short w3t[512 * 64];  // 64 KB, pre-swizzled
    __shared__ __align__(16) unsigned short w2t[64 * 128];  // 16 KB, pre-swizzled
    __shared__ __align__(16) float w1s[384];
    __shared__ __align__(16) float b1s[128];
    __shared__ __align__(16) float b2s[64];
    __shared__ __align__(16) float b3s[512];
    __shared__ __align__(16) unsigned h2st[8][512];         // 2 KB per wave

    const int t = threadIdx.x;
    {
        const uint4* g = (const uint4*)w3t_g;
        uint4* l = (uint4*)w3t;
        for (int v = t; v < 4096; v += 512) l[v] = g[v];
    }
    {
        const uint4* g = (const uint4*)w2t_g;
        uint4* l = (uint4*)w2t;
        for (int v = t; v < 1024; v += 512) l[v] = g[v];
    }
    if (t < 384) w1s[t] = w1[t];
    if (t < 128) b1s[t] = b1[t];
    if (t < 64)  b2s[t] = b2[t];
    b3s[t] = b3[t];
    __syncthreads();

    const int wid = t >> 6, lane = t & 63;
    const int lr = lane & 15, lg = lane >> 4;
    char* h2w = (char*)h2st[wid];
    const int swz = (lr & 7) << 4;

    for (int chunk = blockIdx.x * 8 + wid; chunk < NE / 64; chunk += FUSED_GRID * 8) {
#pragma unroll 1
        for (int st = 0; st < 4; ++st) {
            const int e16 = chunk * 64 + st * 16 + lr;
            const float ea0 = ea[e16 * 3 + 0], ea1 = ea[e16 * 3 + 1], ea2 = ea[e16 * 3 + 2];
            const int sn = src[e16];
            const f32x4* __restrict__ xp = (const f32x4*)(x + (size_t)sn * 16);
            f32x4 x0 = xp[0], x1 = xp[1], x2 = xp[2], x3 = xp[3];

            // ---- L1: h1 fragment (this lane's 32 j-values = B-frags of 4 MFMAs) ----
            s16x8 hb[4];
#pragma unroll
            for (int m = 0; m < 4; ++m) {
                const int j0 = m * 32 + lg * 8;
                f32x4 wa0 = *(const f32x4*)(w1s + j0),       wa1 = *(const f32x4*)(w1s + j0 + 4);
                f32x4 wb0 = *(const f32x4*)(w1s + 128 + j0), wb1 = *(const f32x4*)(w1s + 128 + j0 + 4);
                f32x4 wc0 = *(const f32x4*)(w1s + 256 + j0), wc1 = *(const f32x4*)(w1s + 256 + j0 + 4);
                f32x4 bv0 = *(const f32x4*)(b1s + j0),       bv1 = *(const f32x4*)(b1s + j0 + 4);
#pragma unroll
                for (int i = 0; i < 4; ++i) {
                    float ha = fmaf(ea0, wa0[i], fmaf(ea1, wb0[i], fmaf(ea2, wc0[i], bv0[i])));
                    hb[m][i] = (short)f2bf(fmaxf(ha, 0.f));
                    float hc = fmaf(ea0, wa1[i], fmaf(ea1, wb1[i], fmaf(ea2, wc1[i], bv1[i])));
                    hb[m][i + 4] = (short)f2bf(fmaxf(hc, 0.f));
                }
            }

            // ---- L2: h2 = relu(w2^T @ h1 + b2), 16 MFMAs ----
            f32x4 acc2[4];
#pragma unroll
            for (int fn2 = 0; fn2 < 4; ++fn2)
                acc2[fn2] = *(const f32x4*)(b2s + fn2 * 16 + lg * 4);
#pragma unroll
            for (int m = 0; m < 4; ++m) {
#pragma unroll
                for (int fn2 = 0; fn2 < 4; ++fn2) {
                    const int o = fn2 * 16 + lr;
                    s16x8 a = *(const s16x8*)((const char*)w2t + (o << 8) +
                                              ((m * 64 + lg * 16) ^ ((o & 7) << 4)));
                    acc2[fn2] = __builtin_amdgcn_mfma_f32_16x16x32_bf16(a, hb[m], acc2[fn2], 0, 0, 0);
                }
            }

            // ---- redistribute h2 through slab into w3-GEMM B-fragments ----
            asm volatile("s_waitcnt lgkmcnt(0)" ::: "memory");  // prior subtile's slab reads done
#pragma unroll
            for (int fn2 = 0; fn2 < 4; ++fn2) {
                f32x4 r;
#pragma unroll
                for (int q = 0; q < 4; ++q) r[q] = fmaxf(acc2[fn2][q], 0.f);
                *(uint2*)(h2w + lr * 128 + ((fn2 * 32 + lg * 8) ^ swz)) = pack_bf4(r);
            }
            asm volatile("s_waitcnt lgkmcnt(0)" ::: "memory");
            s16x8 bb0 = *(const s16x8*)(h2w + lr * 128 + ((lg * 16) ^ swz));
            s16x8 bb1 = *(const s16x8*)(h2w + lr * 128 + ((64 + lg * 16) ^ swz));

            // ---- b3 seed: p[o] = sum_i x_i * b3[i*32+o] ----
            f32x4 p0 = (f32x4){0.f, 0.f, 0.f, 0.f};
            f32x4 p1 = (f32x4){0.f, 0.f, 0.f, 0.f};
#pragma unroll
            for (int i = 0; i < 16; ++i) {
                const float xi = (i < 4 ? x0 : i < 8 ? x1 : i < 12 ? x2 : x3)[i & 3];
                f32x4 bv0 = *(const f32x4*)(b3s + i * 32 + lg * 4);
                f32x4 bv1 = *(const f32x4*)(b3s + i * 32 + 16 + lg * 4);
#pragma unroll
                for (int q = 0; q < 4; ++q) {
                    p0[q] = fmaf(xi, bv0[q], p0[q]);
                    p1[q] = fmaf(xi, bv1[q], p1[q]);
                }
            }

            // ---- w3 GEMM + x-contraction ----
#pragma unroll
            for (int fnn = 0; fnn < 32; ++fnn) {
                const int n = fnn * 16 + lr;
                const char* __restrict__ arow = (const char*)w3t + (n << 7);
                const int sw3 = (n & 7) << 4;
                s16x8 a0 = *(const s16x8*)(arow + ((lg * 16) ^ sw3));
                s16x8 a1 = *(const s16x8*)(arow + ((64 + lg * 16) ^ sw3));
                f32x4 am = (f32x4){0.f, 0.f, 0.f, 0.f};
                am = __builtin_amdgcn_mfma_f32_16x16x32_bf16(a0, bb0, am, 0, 0, 0);
                am = __builtin_amdgcn_mfma_f32_16x16x32_bf16(a1, bb1, am, 0, 0, 0);
                const int i = fnn >> 1;
                const float xvv = (i < 4 ? x0 : i < 8 ? x1 : i < 12 ? x2 : x3)[i & 3];
                if (fnn & 1) {
#pragma unroll
                    for (int q = 0; q < 4; ++q) p1[q] = fmaf(xvv, am[q], p1[q]);
                } else {
#pragma unroll
                    for (int q = 0; q < 4; ++q) p0[q] = fmaf(xvv, am[q], p0[q]);
                }
            }

            // ---- LDS transpose -> one contiguous 1KB store ----
            asm volatile("s_waitcnt lgkmcnt(0)" ::: "memory");
            *(uint2*)(h2w + lr * 64 + lg * 8)      = pack_bf4(p0);
            *(uint2*)(h2w + lr * 64 + 32 + lg * 8) = pack_bf4(p1);
            asm volatile("s_waitcnt lgkmcnt(0)" ::: "memory");
            uint4 u = *(const uint4*)(h2w + lane * 16);
            *(uint4*)((char*)msg + (size_t)(chunk * 64 + st * 16) * 64 + lane * 16) = u;
        }
    }
}

// ---------------- aggregate msg by dst (CSR gather) + root transform ----------------
__global__ __launch_bounds__(256) void k_agg(
    const unsigned short* __restrict__ msg, const int* __restrict__ rowptr,
    const int* __restrict__ eid, const float* __restrict__ x,
    const float* __restrict__ rw, const float* __restrict__ cb, float* __restrict__ h1)
{
    const int gid = blockIdx.x * 256 + threadIdx.x;
    const int n = (gid >> 6) * 2 + ((gid & 63) >> 5);  // 2 nodes per wave
    if (n >= NN) return;
    const int o = gid & 31;
    const int r0 = rowptr[n], r1 = rowptr[n + 1];
    float acc = 0.f;
    for (int j = r0; j < r1; ++j)
        acc += bf2f(msg[(size_t)eid[j] * 32 + o]);
    const float* __restrict__ xr = x + (size_t)n * 16;
    float root = cb[o];
#pragma unroll
    for (int i = 0; i < 16; ++i) root = fmaf(xr[i], rw[i * 32 + o], root);
    h1[(size_t)n * 32 + o] = fmaxf(acc + root, 0.f);
}

// ---------------- GAT: node transform + attention coefficients ----------------
template <int FI>
__global__ __launch_bounds__(256) void k_gat_h(
    const float* __restrict__ hin, const float* __restrict__ W,
    const float* __restrict__ av_s, const float* __restrict__ av_d,
    float* __restrict__ h, float* __restrict__ as_v, float* __restrict__ ad_v)
{
    const int n = blockIdx.x * 256 + threadIdx.x;
    if (n >= NN) return;
    float acc[64];
#pragma unroll
    for (int o = 0; o < 64; ++o) acc[o] = 0.f;
#pragma unroll 2
    for (int i = 0; i < FI; ++i) {
        const float xi = hin[(size_t)n * FI + i];
        const float* __restrict__ wr = W + i * 64;
#pragma unroll
        for (int o = 0; o < 64; ++o) acc[o] = fmaf(xi, wr[o], acc[o]);
    }
    float s = 0.f, d = 0.f;
#pragma unroll
    for (int o = 0; o < 64; ++o) {
        h[(size_t)n * 64 + o] = acc[o];
        s = fmaf(acc[o], av_s[o], s);
        d = fmaf(acc[o], av_d[o], d);
    }
    as_v[n] = s;
    ad_v[n] = d;
}

// ---------------- GAT: per-node softmax + weighted gather (one wave per node) ----------------
__global__ __launch_bounds__(256) void k_gat_node(
    const int* __restrict__ rowptr, const int* __restrict__ eid, const int* __restrict__ src,
    const float* __restrict__ h, const float* __restrict__ as_v, const float* __restrict__ ad_v,
    const float* __restrict__ b, float* __restrict__ out)
{
    const int n = (blockIdx.x * 256 + threadIdx.x) >> 6;
    if (n >= NN) return;
    const int lane = threadIdx.x & 63;
    const int r0 = rowptr[n], r1 = rowptr[n + 1];
    const float adn = ad_v[n];
    const float l_self = lrelu(as_v[n] + adn);
    float m = l_self;
    for (int j = r0 + lane; j < r1; j += 64)
        m = fmaxf(m, lrelu(as_v[src[eid[j]]] + adn));
#pragma unroll
    for (int off = 32; off; off >>= 1) m = fmaxf(m, __shfl_xor(m, off));
    float s = 0.f;
    for (int j = r0 + lane; j < r1; j += 64)
        s += expf(lrelu(as_v[src[eid[j]]] + adn) - m);
#pragma unroll
    for (int off = 32; off; off >>= 1) s += __shfl_xor(s, off);
    const float w_self = expf(l_self - m);
    s += w_self;
    float acc = w_self * h[(size_t)n * 64 + lane];
    for (int j = r0; j < r1; ++j) {
        const int sn = src[eid[j]];
        const float w = expf(lrelu(as_v[sn] + adn) - m);
        acc = fmaf(w, h[(size_t)sn * 64 + lane], acc);
    }
    out[(size_t)n * 64 + lane] = fmaxf(acc / s + b[lane], 0.f);
}

// ---------------- global mean pool ----------------
__global__ __launch_bounds__(256) void k_pool1(
    const float* __restrict__ h, const int* __restrict__ batch,
    float* __restrict__ gsum, float* __restrict__ gcnt)
{
    __shared__ float ls[NG * 64];
    __shared__ float lc[NG];
    for (int j = threadIdx.x; j < NG * 64; j += 256) ls[j] = 0.f;
    if (threadIdx.x < NG) lc[threadIdx.x] = 0.f;
    __syncthreads();
    const int base = blockIdx.x * 512;
    for (int idx = threadIdx.x; idx < 512 * 64; idx += 256) {
        const int nl = idx >> 6, f = idx & 63;
        const int n = base + nl;
        if (n < NN) {
            const int g = batch[n];
            atomicAdd(&ls[g * 64 + f], h[(size_t)n * 64 + f]);
            if (f == 0) atomicAdd(&lc[g], 1.f);
        }
    }
    __syncthreads();
    for (int j = threadIdx.x; j < NG * 64; j += 256) atomicAdd(&gsum[j], ls[j]);
    if (threadIdx.x < NG) atomicAdd(&gcnt[threadIdx.x], lc[threadIdx.x]);
}

__global__ __launch_bounds__(256) void k_pool2(
    const float* __restrict__ gsum, const float* __restrict__ gcnt, float* __restrict__ out)
{
    const int idx = blockIdx.x * 256 + threadIdx.x;
    if (idx >= NG * 64) return;
    out[idx] = gsum[idx] / fmaxf(gcnt[idx >> 6], 1.f);
}

extern "C" void kernel_launch(void* const* d_in, const int* in_sizes, int n_in,
                              void* d_out, int out_size, void* d_ws, size_t ws_size,
                              hipStream_t stream)
{
    const float* x     = (const float*)d_in[0];
    const float* ea    = (const float*)d_in[1];
    const int*   ei    = (const int*)d_in[2];
    const int*   batch = (const int*)d_in[3];
    const float* w1 = (const float*)d_in[4];   const float* b1 = (const float*)d_in[5];
    const float* w2 = (const float*)d_in[6];   const float* b2 = (const float*)d_in[7];
    const float* w3 = (const float*)d_in[8];   const float* b3 = (const float*)d_in[9];
    const float* rw = (const float*)d_in[10];  const float* cb = (const float*)d_in[11];
    const float* g1w  = (const float*)d_in[12]; const float* g1as = (const float*)d_in[13];
    const float* g1ad = (const float*)d_in[14]; const float* g1b  = (const float*)d_in[15];
    const float* g2w  = (const float*)d_in[16]; const float* g2as = (const float*)d_in[17];
    const float* g2ad = (const float*)d_in[18]; const float* g2b  = (const float*)d_in[19];
    const int* src = ei;
    const int* dst = ei + NE;
    float* out = (float*)d_out;
    (void)in_sizes; (void)n_in; (void)out_size; (void)ws_size;

    char* ws = (char*)d_ws;
    size_t off = 0;
    auto alloc = [&](size_t bytes) -> char* {
        char* p = ws + off;
        off += (bytes + 255) & ~(size_t)255;
        return p;
    };
    int*  deg    = (int*)alloc((size_t)NN * 4);
    int*  cursor = (int*)alloc((size_t)NN * 4);
    int*  rowptr = (int*)alloc((size_t)(NN + 1) * 4);
    int*  eid    = (int*)alloc((size_t)NE * 4);
    unsigned short* w3t_g = (unsigned short*)alloc((size_t)64 * 512 * 2);
    unsigned short* w2t_g = (unsigned short*)alloc((size_t)64 * 128 * 2);
    unsigned short* msg   = (unsigned short*)alloc((size_t)NE * 32 * 2);  // 25.6 MB
    float* h1   = (float*)alloc((size_t)NN * 32 * 4);
    float* hB   = (float*)alloc((size_t)NN * 64 * 4);
    float* hC   = (float*)alloc((size_t)NN * 64 * 4);
    float* hD   = (float*)alloc((size_t)NN * 64 * 4);
    float* as_v = (float*)alloc((size_t)NN * 4);
    float* ad_v = (float*)alloc((size_t)NN * 4);
    float* gsum = (float*)alloc((size_t)NG * 64 * 4);
    float* gcnt = (float*)alloc((size_t)NG * 4);

    hipMemsetAsync(deg, 0, (size_t)NN * 4, stream);
    hipMemsetAsync(gsum, 0, (size_t)NG * 64 * 4, stream);
    hipMemsetAsync(gcnt, 0, (size_t)NG * 4, stream);

    // CSR build
    k_hist<<<(NE + 255) / 256, 256, 0, stream>>>(dst, deg);
    k_scan<<<1, 1024, 0, stream>>>(deg, rowptr, cursor);
    k_perm<<<(NE + 255) / 256, 256, 0, stream>>>(dst, cursor, eid);

    // NNConv (fused MLP + GEMM)
    k_wprep<<<(64 * 512 + 255) / 256, 256, 0, stream>>>(w3, w2, w3t_g, w2t_g);
    k_fused<<<FUSED_GRID, 512, 0, stream>>>(ea, w1, b1, w2t_g, b2, w3t_g, b3, src, x, msg);
    k_agg<<<(NN / 2 * 64 + 255) / 256 + 1, 256, 0, stream>>>(msg, rowptr, eid, x, rw, cb, h1);

    // GAT layer 1
    k_gat_h<32><<<(NN + 255) / 256, 256, 0, stream>>>(h1, g1w, g1as, g1ad, hB, as_v, ad_v);
    k_gat_node<<<(NN * 64 + 255) / 256, 256, 0, stream>>>(rowptr, eid, src, hB, as_v, ad_v, g1b, hC);

    // GAT layer 2
    k_gat_h<64><<<(NN + 255) / 256, 256, 0, stream>>>(hC, g2w, g2as, g2ad, hB, as_v, ad_v);
    k_gat_node<<<(NN * 64 + 255) / 256, 256, 0, stream>>>(rowptr, eid, src, hB, as_v, ad_v, g2b, hD);

    // pool
    k_pool1<<<(NN + 511) / 512, 256, 0, stream>>>(hD, batch, gsum, gcnt);
    k_pool2<<<(NG * 64 + 255) / 256, 256, 0, stream>>>(gsum, gcnt, out);
}

// Round 7
// 410.063 us; speedup vs baseline: 2.1848x; 1.3434x over previous
//
#include <hip/hip_runtime.h>

#define NN 50000
#define NE 400000
#define NG 32
#define SLOPE 0.2f
#define NSB ((NN + 255) / 256)   // 196 scan blocks

typedef __attribute__((ext_vector_type(4))) float f32x4;
typedef __attribute__((ext_vector_type(8))) short s16x8;

__device__ __forceinline__ float lrelu(float v) { return v > 0.f ? v : SLOPE * v; }
__device__ __forceinline__ unsigned short f2bf(float f) {
    union { float f; unsigned u; } c; c.f = f;
    unsigned r = c.u + 0x7fffu + ((c.u >> 16) & 1u);
    return (unsigned short)(r >> 16);
}
__device__ __forceinline__ float bf2f(unsigned short b) {
    union { unsigned u; float f; } c; c.u = ((unsigned)b) << 16; return c.f;
}
__device__ __forceinline__ uint2 pack_bf4(f32x4 v) {
    uint2 u;
    u.x = (unsigned)f2bf(v[0]) | ((unsigned)f2bf(v[1]) << 16);
    u.y = (unsigned)f2bf(v[2]) | ((unsigned)f2bf(v[3]) << 16);
    return u;
}

// ---------------- CSR build ----------------
__global__ __launch_bounds__(256) void k_hist(const int* __restrict__ dst, int* __restrict__ deg) {
    int e = blockIdx.x * 256 + threadIdx.x;
    if (e < NE) atomicAdd(&deg[dst[e]], 1);
}

// per-256-chunk totals
__global__ __launch_bounds__(256) void k_bsum(const int* __restrict__ deg, int* __restrict__ bsum) {
    __shared__ int ls[256];
    const int t = threadIdx.x;
    const int idx = blockIdx.x * 256 + t;
    ls[t] = (idx < NN) ? deg[idx] : 0;
    __syncthreads();
#pragma unroll
    for (int off = 128; off; off >>= 1) {
        if (t < off) ls[t] += ls[t + off];
        __syncthreads();
    }
    if (t == 0) bsum[blockIdx.x] = ls[0];
}

// per-block: offset = sum(bsum[0..b-1]) + local Hillis-Steele scan -> rowptr/cursor
__global__ __launch_bounds__(256) void k_scan2(const int* __restrict__ deg,
                                               const int* __restrict__ bsum,
                                               int* __restrict__ rowptr, int* __restrict__ cursor) {
    __shared__ int lb[256];
    __shared__ int ls[256];
    const int t = threadIdx.x, b = blockIdx.x;
    lb[t] = (t < NSB && t < b) ? bsum[t] : 0;
    const int idx = b * 256 + t;
    const int v = (idx < NN) ? deg[idx] : 0;
    ls[t] = v;
    __syncthreads();
#pragma unroll
    for (int off = 128; off; off >>= 1) {
        if (t < off) lb[t] += lb[t + off];
        __syncthreads();
    }
#pragma unroll
    for (int off = 1; off < 256; off <<= 1) {
        int u = (t >= off) ? ls[t - off] : 0;
        __syncthreads();
        ls[t] += u;
        __syncthreads();
    }
    if (idx < NN) {
        const int run = lb[0] + ls[t] - v;  // exclusive prefix
        rowptr[idx] = run;
        cursor[idx] = run;
    }
    if (b == 0 && t == 0) rowptr[NN] = NE;
}

__global__ __launch_bounds__(256) void k_perm(const int* __restrict__ dst,
                                              int* __restrict__ cursor, int* __restrict__ eid) {
    int e = blockIdx.x * 256 + threadIdx.x;
    if (e < NE) { int p = atomicAdd(&cursor[dst[e]], 1); eid[p] = e; }
}

// ---------------- one-time: w3 and w2^T -> bf16, row-major, XOR-swizzled ----------------
__global__ __launch_bounds__(256) void k_wprep(const float* __restrict__ w3,
                                               const float* __restrict__ w2,
                                               unsigned short* __restrict__ w3t_g,
                                               unsigned short* __restrict__ w2t_g) {
    const int v = blockIdx.x * 256 + threadIdx.x;
    if (v < 64 * 512) {  // w3: v = k*512 + n -> w3t[n][k]
        const int k = v >> 9, n = v & 511;
        const int byte = (n << 7) | ((k << 1) ^ ((n & 7) << 4));
        *(unsigned short*)((char*)w3t_g + byte) = f2bf(w3[v]);
    }
    if (v < 128 * 64) {  // w2: v = j*64 + o -> w2t[o][j]
        const int j = v >> 6, o = v & 63;
        const int byte = (o << 8) | ((j << 1) ^ ((o & 7) << 4));
        *(unsigned short*)((char*)w2t_g + byte) = f2bf(w2[v]);
    }
}

// ---------------- fused NNConv edge pipeline: MLP(L1 scalar, L2 MFMA) -> w3 MFMA -> msg ----------
#define FUSED_GRID 256
__global__ __launch_bounds__(512) void k_fused(
    const float* __restrict__ ea,
    const float* __restrict__ w1, const float* __restrict__ b1,
    const unsigned short* __restrict__ w2t_g, const float* __restrict__ b2,
    const unsigned short* __restrict__ w3t_g, const float* __restrict__ b3,
    const int* __restrict__ src, const float* __restrict__ x,
    unsigned short* __restrict__ msg)
{
    __shared__ __align__(16) unsigned short w3t[512 * 64];  // 64 KB, pre-swizzled
    __shared__ __align__(16) unsigned short w2t[64 * 128];  // 16 KB, pre-swizzled
    __shared__ __align__(16) float w1s[384];
    __shared__ __align__(16) float b1s[128];
    __shared__ __align__(16) float b2s[64];
    __shared__ __align__(16) float b3s[512];
    __shared__ __align__(16) unsigned h2st[8][512];         // 2 KB per wave

    const int t = threadIdx.x;
    {
        const uint4* g = (const uint4*)w3t_g;
        uint4* l = (uint4*)w3t;
        for (int v = t; v < 4096; v += 512) l[v] = g[v];
    }
    {
        const uint4* g = (const uint4*)w2t_g;
        uint4* l = (uint4*)w2t;
        for (int v = t; v < 1024; v += 512) l[v] = g[v];
    }
    if (t < 384) w1s[t] = w1[t];
    if (t < 128) b1s[t] = b1[t];
    if (t < 64)  b2s[t] = b2[t];
    b3s[t] = b3[t];
    __syncthreads();

    const int wid = t >> 6, lane = t & 63;
    const int lr = lane & 15, lg = lane >> 4;
    char* h2w = (char*)h2st[wid];
    const int swz = (lr & 7) << 4;

    for (int chunk = blockIdx.x * 8 + wid; chunk < NE / 64; chunk += FUSED_GRID * 8) {
#pragma unroll 1
        for (int st = 0; st < 4; ++st) {
            const int e16 = chunk * 64 + st * 16 + lr;
            const float ea0 = ea[e16 * 3 + 0], ea1 = ea[e16 * 3 + 1], ea2 = ea[e16 * 3 + 2];
            const int sn = src[e16];
            const f32x4* __restrict__ xp = (const f32x4*)(x + (size_t)sn * 16);
            f32x4 x0 = xp[0], x1 = xp[1], x2 = xp[2], x3 = xp[3];

            // ---- L1: h1 fragment ----
            s16x8 hb[4];
#pragma unroll
            for (int m = 0; m < 4; ++m) {
                const int j0 = m * 32 + lg * 8;
                f32x4 wa0 = *(const f32x4*)(w1s + j0),       wa1 = *(const f32x4*)(w1s + j0 + 4);
                f32x4 wb0 = *(const f32x4*)(w1s + 128 + j0), wb1 = *(const f32x4*)(w1s + 128 + j0 + 4);
                f32x4 wc0 = *(const f32x4*)(w1s + 256 + j0), wc1 = *(const f32x4*)(w1s + 256 + j0 + 4);
                f32x4 bv0 = *(const f32x4*)(b1s + j0),       bv1 = *(const f32x4*)(b1s + j0 + 4);
#pragma unroll
                for (int i = 0; i < 4; ++i) {
                    float ha = fmaf(ea0, wa0[i], fmaf(ea1, wb0[i], fmaf(ea2, wc0[i], bv0[i])));
                    hb[m][i] = (short)f2bf(fmaxf(ha, 0.f));
                    float hc = fmaf(ea0, wa1[i], fmaf(ea1, wb1[i], fmaf(ea2, wc1[i], bv1[i])));
                    hb[m][i + 4] = (short)f2bf(fmaxf(hc, 0.f));
                }
            }

            // ---- L2: h2 = relu(w2^T @ h1 + b2), 16 MFMAs ----
            f32x4 acc2[4];
#pragma unroll
            for (int fn2 = 0; fn2 < 4; ++fn2)
                acc2[fn2] = *(const f32x4*)(b2s + fn2 * 16 + lg * 4);
#pragma unroll
            for (int m = 0; m < 4; ++m) {
#pragma unroll
                for (int fn2 = 0; fn2 < 4; ++fn2) {
                    const int o = fn2 * 16 + lr;
                    s16x8 a = *(const s16x8*)((const char*)w2t + (o << 8) +
                                              ((m * 64 + lg * 16) ^ ((o & 7) << 4)));
                    acc2[fn2] = __builtin_amdgcn_mfma_f32_16x16x32_bf16(a, hb[m], acc2[fn2], 0, 0, 0);
                }
            }

            // ---- redistribute h2 through slab into w3-GEMM B-fragments ----
            asm volatile("s_waitcnt lgkmcnt(0)" ::: "memory");
#pragma unroll
            for (int fn2 = 0; fn2 < 4; ++fn2) {
                f32x4 r;
#pragma unroll
                for (int q = 0; q < 4; ++q) r[q] = fmaxf(acc2[fn2][q], 0.f);
                *(uint2*)(h2w + lr * 128 + ((fn2 * 32 + lg * 8) ^ swz)) = pack_bf4(r);
            }
            asm volatile("s_waitcnt lgkmcnt(0)" ::: "memory");
            s16x8 bb0 = *(const s16x8*)(h2w + lr * 128 + ((lg * 16) ^ swz));
            s16x8 bb1 = *(const s16x8*)(h2w + lr * 128 + ((64 + lg * 16) ^ swz));

            // ---- b3 seed: p[o] = sum_i x_i * b3[i*32+o] ----
            f32x4 p0 = (f32x4){0.f, 0.f, 0.f, 0.f};
            f32x4 p1 = (f32x4){0.f, 0.f, 0.f, 0.f};
#pragma unroll
            for (int i = 0; i < 16; ++i) {
                const float xi = (i < 4 ? x0 : i < 8 ? x1 : i < 12 ? x2 : x3)[i & 3];
                f32x4 bv0 = *(const f32x4*)(b3s + i * 32 + lg * 4);
                f32x4 bv1 = *(const f32x4*)(b3s + i * 32 + 16 + lg * 4);
#pragma unroll
                for (int q = 0; q < 4; ++q) {
                    p0[q] = fmaf(xi, bv0[q], p0[q]);
                    p1[q] = fmaf(xi, bv1[q], p1[q]);
                }
            }

            // ---- w3 GEMM + x-contraction ----
#pragma unroll
            for (int fnn = 0; fnn < 32; ++fnn) {
                const int n = fnn * 16 + lr;
                const char* __restrict__ arow = (const char*)w3t + (n << 7);
                const int sw3 = (n & 7) << 4;
                s16x8 a0 = *(const s16x8*)(arow + ((lg * 16) ^ sw3));
                s16x8 a1 = *(const s16x8*)(arow + ((64 + lg * 16) ^ sw3));
                f32x4 am = (f32x4){0.f, 0.f, 0.f, 0.f};
                am = __builtin_amdgcn_mfma_f32_16x16x32_bf16(a0, bb0, am, 0, 0, 0);
                am = __builtin_amdgcn_mfma_f32_16x16x32_bf16(a1, bb1, am, 0, 0, 0);
                const int i = fnn >> 1;
                const float xvv = (i < 4 ? x0 : i < 8 ? x1 : i < 12 ? x2 : x3)[i & 3];
                if (fnn & 1) {
#pragma unroll
                    for (int q = 0; q < 4; ++q) p1[q] = fmaf(xvv, am[q], p1[q]);
                } else {
#pragma unroll
                    for (int q = 0; q < 4; ++q) p0[q] = fmaf(xvv, am[q], p0[q]);
                }
            }

            // ---- LDS transpose -> one contiguous 1KB store ----
            asm volatile("s_waitcnt lgkmcnt(0)" ::: "memory");
            *(uint2*)(h2w + lr * 64 + lg * 8)      = pack_bf4(p0);
            *(uint2*)(h2w + lr * 64 + 32 + lg * 8) = pack_bf4(p1);
            asm volatile("s_waitcnt lgkmcnt(0)" ::: "memory");
            uint4 u = *(const uint4*)(h2w + lane * 16);
            *(uint4*)((char*)msg + (size_t)(chunk * 64 + st * 16) * 64 + lane * 16) = u;
        }
    }
}

// ---------------- aggregate msg by dst (CSR gather) + root transform ----------------
__global__ __launch_bounds__(256) void k_agg(
    const unsigned short* __restrict__ msg, const int* __restrict__ rowptr,
    const int* __restrict__ eid, const float* __restrict__ x,
    const float* __restrict__ rw, const float* __restrict__ cb, float* __restrict__ h1)
{
    const int gid = blockIdx.x * 256 + threadIdx.x;
    const int n = (gid >> 6) * 2 + ((gid & 63) >> 5);  // 2 nodes per wave
    if (n >= NN) return;
    const int o = gid & 31;
    const int r0 = rowptr[n], r1 = rowptr[n + 1];
    float acc = 0.f;
    for (int j = r0; j < r1; ++j)
        acc += bf2f(msg[(size_t)eid[j] * 32 + o]);
    const float* __restrict__ xr = x + (size_t)n * 16;
    float root = cb[o];
#pragma unroll
    for (int i = 0; i < 16; ++i) root = fmaf(xr[i], rw[i * 32 + o], root);
    h1[(size_t)n * 32 + o] = fmaxf(acc + root, 0.f);
}

// ---------------- GAT: node transform + attention coefficients ----------------
template <int FI>
__global__ __launch_bounds__(256) void k_gat_h(
    const float* __restrict__ hin, const float* __restrict__ W,
    const float* __restrict__ av_s, const float* __restrict__ av_d,
    float* __restrict__ h, float* __restrict__ as_v, float* __restrict__ ad_v)
{
    const int n = blockIdx.x * 256 + threadIdx.x;
    if (n >= NN) return;
    float acc[64];
#pragma unroll
    for (int o = 0; o < 64; ++o) acc[o] = 0.f;
    const f32x4* __restrict__ hp = (const f32x4*)(hin + (size_t)n * FI);
#pragma unroll 2
    for (int i4 = 0; i4 < FI / 4; ++i4) {
        f32x4 xi = hp[i4];
#pragma unroll
        for (int c = 0; c < 4; ++c) {
            const float xv = xi[c];
            const float* __restrict__ wr = W + (i4 * 4 + c) * 64;
#pragma unroll
            for (int o = 0; o < 64; ++o) acc[o] = fmaf(xv, wr[o], acc[o]);
        }
    }
    float s = 0.f, d = 0.f;
#pragma unroll
    for (int o = 0; o < 64; ++o) {
        h[(size_t)n * 64 + o] = acc[o];
        s = fmaf(acc[o], av_s[o], s);
        d = fmaf(acc[o], av_d[o], d);
    }
    as_v[n] = s;
    ad_v[n] = d;
}

// ---------------- GAT: per-node softmax + weighted gather (one wave per node) ----------------
__global__ __launch_bounds__(256) void k_gat_node(
    const int* __restrict__ rowptr, const int* __restrict__ eid, const int* __restrict__ src,
    const float* __restrict__ h, const float* __restrict__ as_v, const float* __restrict__ ad_v,
    const float* __restrict__ b, float* __restrict__ out)
{
    const int n = (blockIdx.x * 256 + threadIdx.x) >> 6;
    if (n >= NN) return;
    const int lane = threadIdx.x & 63;
    const int r0 = rowptr[n], r1 = rowptr[n + 1];
    const float adn = ad_v[n];
    const float l_self = lrelu(as_v[n] + adn);
    float m = l_self;
    for (int j = r0 + lane; j < r1; j += 64)
        m = fmaxf(m, lrelu(as_v[src[eid[j]]] + adn));
#pragma unroll
    for (int off = 32; off; off >>= 1) m = fmaxf(m, __shfl_xor(m, off));
    float s = 0.f;
    for (int j = r0 + lane; j < r1; j += 64)
        s += expf(lrelu(as_v[src[eid[j]]] + adn) - m);
#pragma unroll
    for (int off = 32; off; off >>= 1) s += __shfl_xor(s, off);
    const float w_self = expf(l_self - m);
    s += w_self;
    float acc = w_self * h[(size_t)n * 64 + lane];
    for (int j = r0; j < r1; ++j) {
        const int sn = src[eid[j]];
        const float w = expf(lrelu(as_v[sn] + adn) - m);
        acc = fmaf(w, h[(size_t)sn * 64 + lane], acc);
    }
    out[(size_t)n * 64 + lane] = fmaxf(acc / s + b[lane], 0.f);
}

// ---------------- global mean pool ----------------
__global__ __launch_bounds__(256) void k_pool1(
    const float* __restrict__ h, const int* __restrict__ batch,
    float* __restrict__ gsum, float* __restrict__ gcnt)
{
    __shared__ float ls[NG * 64];
    __shared__ float lc[NG];
    for (int j = threadIdx.x; j < NG * 64; j += 256) ls[j] = 0.f;
    if (threadIdx.x < NG) lc[threadIdx.x] = 0.f;
    __syncthreads();
    const int base = blockIdx.x * 512;
    for (int idx = threadIdx.x; idx < 512 * 64; idx += 256) {
        const int nl = idx >> 6, f = idx & 63;
        const int n = base + nl;
        if (n < NN) {
            const int g = batch[n];
            atomicAdd(&ls[g * 64 + f], h[(size_t)n * 64 + f]);
            if (f == 0) atomicAdd(&lc[g], 1.f);
        }
    }
    __syncthreads();
    for (int j = threadIdx.x; j < NG * 64; j += 256) atomicAdd(&gsum[j], ls[j]);
    if (threadIdx.x < NG) atomicAdd(&gcnt[threadIdx.x], lc[threadIdx.x]);
}

__global__ __launch_bounds__(256) void k_pool2(
    const float* __restrict__ gsum, const float* __restrict__ gcnt, float* __restrict__ out)
{
    const int idx = blockIdx.x * 256 + threadIdx.x;
    if (idx >= NG * 64) return;
    out[idx] = gsum[idx] / fmaxf(gcnt[idx >> 6], 1.f);
}

extern "C" void kernel_launch(void* const* d_in, const int* in_sizes, int n_in,
                              void* d_out, int out_size, void* d_ws, size_t ws_size,
                              hipStream_t stream)
{
    const float* x     = (const float*)d_in[0];
    const float* ea    = (const float*)d_in[1];
    const int*   ei    = (const int*)d_in[2];
    const int*   batch = (const int*)d_in[3];
    const float* w1 = (const float*)d_in[4];   const float* b1 = (const float*)d_in[5];
    const float* w2 = (const float*)d_in[6];   const float* b2 = (const float*)d_in[7];
    const float* w3 = (const float*)d_in[8];   const float* b3 = (const float*)d_in[9];
    const float* rw = (const float*)d_in[10];  const float* cb = (const float*)d_in[11];
    const float* g1w  = (const float*)d_in[12]; const float* g1as = (const float*)d_in[13];
    const float* g1ad = (const float*)d_in[14]; const float* g1b  = (const float*)d_in[15];
    const float* g2w  = (const float*)d_in[16]; const float* g2as = (const float*)d_in[17];
    const float* g2ad = (const float*)d_in[18]; const float* g2b  = (const float*)d_in[19];
    const int* src = ei;
    const int* dst = ei + NE;
    float* out = (float*)d_out;
    (void)in_sizes; (void)n_in; (void)out_size; (void)ws_size;

    char* ws = (char*)d_ws;
    size_t off = 0;
    auto alloc = [&](size_t bytes) -> char* {
        char* p = ws + off;
        off += (bytes + 255) & ~(size_t)255;
        return p;
    };
    int*  deg    = (int*)alloc((size_t)NN * 4);
    int*  cursor = (int*)alloc((size_t)NN * 4);
    int*  rowptr = (int*)alloc((size_t)(NN + 1) * 4);
    int*  bsum   = (int*)alloc((size_t)NSB * 4);
    int*  eid    = (int*)alloc((size_t)NE * 4);
    unsigned short* w3t_g = (unsigned short*)alloc((size_t)64 * 512 * 2);
    unsigned short* w2t_g = (unsigned short*)alloc((size_t)64 * 128 * 2);
    unsigned short* msg   = (unsigned short*)alloc((size_t)NE * 32 * 2);  // 25.6 MB
    float* h1   = (float*)alloc((size_t)NN * 32 * 4);
    float* hB   = (float*)alloc((size_t)NN * 64 * 4);
    float* hC   = (float*)alloc((size_t)NN * 64 * 4);
    float* hD   = (float*)alloc((size_t)NN * 64 * 4);
    float* as_v = (float*)alloc((size_t)NN * 4);
    float* ad_v = (float*)alloc((size_t)NN * 4);
    float* gsum = (float*)alloc((size_t)NG * 64 * 4);
    float* gcnt = (float*)alloc((size_t)NG * 4);

    hipMemsetAsync(deg, 0, (size_t)NN * 4, stream);
    hipMemsetAsync(gsum, 0, (size_t)NG * 64 * 4, stream);
    hipMemsetAsync(gcnt, 0, (size_t)NG * 4, stream);

    // CSR build (parallel hierarchical scan)
    k_hist<<<(NE + 255) / 256, 256, 0, stream>>>(dst, deg);
    k_bsum<<<NSB, 256, 0, stream>>>(deg, bsum);
    k_scan2<<<NSB, 256, 0, stream>>>(deg, bsum, rowptr, cursor);
    k_perm<<<(NE + 255) / 256, 256, 0, stream>>>(dst, cursor, eid);

    // NNConv (fused MLP + GEMM)
    k_wprep<<<(64 * 512 + 255) / 256, 256, 0, stream>>>(w3, w2, w3t_g, w2t_g);
    k_fused<<<FUSED_GRID, 512, 0, stream>>>(ea, w1, b1, w2t_g, b2, w3t_g, b3, src, x, msg);
    k_agg<<<(NN / 2 * 64 + 255) / 256 + 1, 256, 0, stream>>>(msg, rowptr, eid, x, rw, cb, h1);

    // GAT layer 1
    k_gat_h<32><<<(NN + 255) / 256, 256, 0, stream>>>(h1, g1w, g1as, g1ad, hB, as_v, ad_v);
    k_gat_node<<<(NN * 64 + 255) / 256, 256, 0, stream>>>(rowptr, eid, src, hB, as_v, ad_v, g1b, hC);

    // GAT layer 2
    k_gat_h<64><<<(NN + 255) / 256, 256, 0, stream>>>(hC, g2w, g2as, g2ad, hB, as_v, ad_v);
    k_gat_node<<<(NN * 64 + 255) / 256, 256, 0, stream>>>(rowptr, eid, src, hB, as_v, ad_v, g2b, hD);

    // pool
    k_pool1<<<(NN + 511) / 512, 256, 0, stream>>>(hD, batch, gsum, gcnt);
    k_pool2<<<(NG * 64 + 255) / 256, 256, 0, stream>>>(gsum, gcnt, out);
}